// Round 1
// baseline (4866.854 us; speedup 1.0000x reference)
//
#include <hip/hip_runtime.h>
#include <math.h>
#include <float.h>

// Problem constants
#define BATCH 16
#define CHN   256
#define HH    32
#define WW    32
#define NTOK  (BATCH*HH*WW)   // 16384 tokens
#define DIMS  256             // embedding dim
#define KCODES 8192           // codebook entries

// Argmin GEMM tiling
#define MBLK 64               // tokens per block
#define NSPLIT 4              // code-range splits (grid = 256*4 = 1024 blocks)
#define CODES_PER_SPLIT (KCODES/NSPLIT)  // 2048
#define NCHUNK 64             // codes per score-tile chunk
#define KS 32                 // K-step (dims per LDS stage)
#define LDP 36                // LDS row stride in floats (36*4=144B: 16B-aligned, conflict-friendly)

#define GATHER_BLOCKS 4096

// Workspace layout (bytes)
#define WS_CB2   0
#define WS_BESTV (32768)
#define WS_BESTI (WS_BESTV + NSPLIT*NTOK*4)
#define WS_IDX   (WS_BESTI + NSPLIT*NTOK*4)
#define WS_PART  (WS_IDX + NTOK*4)
// total = 622592 + 16384 = 638976 bytes

// ---------------------------------------------------------------------------
// Kernel 1: cb2[k] = sum_d codebook[k][d]^2. One wave per row.
__global__ void cb2_kernel(const float* __restrict__ codebook, float* __restrict__ cb2) {
    int wv   = threadIdx.x >> 6;          // 0..3
    int lane = threadIdx.x & 63;
    int row  = blockIdx.x * 4 + wv;       // grid = 2048 blocks -> 8192 rows
    const float4 v = *(const float4*)&codebook[(size_t)row * DIMS + lane * 4];
    float s = v.x*v.x + v.y*v.y + v.z*v.z + v.w*v.w;
    #pragma unroll
    for (int m = 32; m >= 1; m >>= 1) s += __shfl_xor(s, m, 64);
    if (lane == 0) cb2[row] = s;
}

// ---------------------------------------------------------------------------
// Kernel 2: fused distance-GEMM + running argmin.
// Block: 256 threads (4 waves). Computes 64 tokens x 2048 codes.
// score = cb2[k] - 2 * dot(x, c_k)  (x^2 omitted: constant per row)
__global__ __launch_bounds__(256, 4) void argmin_kernel(
    const float* __restrict__ latent, const float* __restrict__ codebook,
    const float* __restrict__ cb2,
    float* __restrict__ bestv_ws, int* __restrict__ besti_ws)
{
    __shared__ float As[MBLK][LDP];    // token tile  (64 x 32 + pad)
    __shared__ float Bs[NCHUNK][LDP];  // code tile   (64 x 32 + pad)

    const int tid = threadIdx.x;
    const int ty = tid >> 4;           // 0..15 -> rows {ty, ty+16, ty+32, ty+48}
    const int tx = tid & 15;           // 0..15 -> cols {tx, tx+16, tx+32, tx+48}
    const int bm = blockIdx.x >> 2;    // token block (0..255)
    const int js = blockIdx.x & 3;     // code split  (0..3)
    const int n0 = bm * MBLK;
    const int cbase = js * CODES_PER_SPLIT;

    const int bb  = n0 >> 10;          // batch index (constant within block)
    const int hw0 = n0 & 1023;         // h*32+w base

    float bestv[4];
    int   besti[4];
    #pragma unroll
    for (int i = 0; i < 4; ++i) { bestv[i] = FLT_MAX; besti[i] = 0x7fffffff; }

    // staging maps
    const int at = tid & 63;           // token (A staging) -- coalesced 256B per wave
    const int ad = tid >> 6;           // d base 0..3
    const int bcode = tid >> 5;        // 0..7
    const int bd = tid & 31;           // d within K-step

    const float* lat_base = latent + (size_t)bb * (CHN*HH*WW) + hw0 + at;  // + d*1024

    for (int ch = 0; ch < CODES_PER_SPLIT / NCHUNK; ++ch) {
        const int code0 = cbase + ch * NCHUNK;
        float acc[4][4];
        #pragma unroll
        for (int i = 0; i < 4; ++i)
            #pragma unroll
            for (int j = 0; j < 4; ++j) acc[i][j] = 0.0f;

        for (int kk = 0; kk < DIMS; kk += KS) {
            // stage A: latent is (b, d, h, w) -> channel-strided gather, coalesced over tokens
            #pragma unroll
            for (int r = 0; r < 8; ++r) {
                int dd = ad + 4 * r;
                As[at][dd] = lat_base[(size_t)(kk + dd) * (HH*WW)];
            }
            // stage B: codebook row-major, coalesced 128B segments
            #pragma unroll
            for (int r = 0; r < 8; ++r) {
                int cc = bcode + 8 * r;
                Bs[cc][bd] = codebook[(size_t)(code0 + cc) * DIMS + kk + bd];
            }
            __syncthreads();

            #pragma unroll
            for (int k4 = 0; k4 < KS; k4 += 4) {
                float4 av[4], bv[4];
                #pragma unroll
                for (int i = 0; i < 4; ++i) av[i] = *(const float4*)&As[ty + 16*i][k4];
                #pragma unroll
                for (int j = 0; j < 4; ++j) bv[j] = *(const float4*)&Bs[tx + 16*j][k4];
                #pragma unroll
                for (int i = 0; i < 4; ++i)
                    #pragma unroll
                    for (int j = 0; j < 4; ++j)
                        acc[i][j] += av[i].x*bv[j].x + av[i].y*bv[j].y
                                   + av[i].z*bv[j].z + av[i].w*bv[j].w;
            }
            __syncthreads();
        }

        // fold cb2 and update running argmin (np.argmin tie rule: first occurrence)
        #pragma unroll
        for (int j = 0; j < 4; ++j) {
            int code = code0 + tx + 16*j;
            float c2 = cb2[code];
            #pragma unroll
            for (int i = 0; i < 4; ++i) {
                float v = c2 - 2.0f * acc[i][j];
                if (v < bestv[i] || (v == bestv[i] && code < besti[i])) {
                    bestv[i] = v; besti[i] = code;
                }
            }
        }
    }

    // reduce across the 16 tx lanes per row (butterfly within 16-lane groups)
    #pragma unroll
    for (int i = 0; i < 4; ++i) {
        float v = bestv[i]; int ix = besti[i];
        #pragma unroll
        for (int m = 8; m >= 1; m >>= 1) {
            float ov = __shfl_xor(v, m, 64);
            int   oi = __shfl_xor(ix, m, 64);
            if (ov < v || (ov == v && oi < ix)) { v = ov; ix = oi; }
        }
        if (tx == 0) {
            int n = n0 + ty + 16*i;
            bestv_ws[js * NTOK + n] = v;
            besti_ws[js * NTOK + n] = ix;
        }
    }
}

// ---------------------------------------------------------------------------
// Kernel 3: combine the NSPLIT partial argmins per token.
__global__ void combine_kernel(const float* __restrict__ bestv_ws,
                               const int* __restrict__ besti_ws,
                               int* __restrict__ idx_ws)
{
    int n = blockIdx.x * 256 + threadIdx.x;
    float v = bestv_ws[n];
    int  ix = besti_ws[n];
    #pragma unroll
    for (int js = 1; js < NSPLIT; ++js) {
        float ov = bestv_ws[js * NTOK + n];
        int   oi = besti_ws[js * NTOK + n];
        if (ov < v || (ov == v && oi < ix)) { v = ov; ix = oi; }
    }
    idx_ws[n] = ix;
}

// ---------------------------------------------------------------------------
// Kernel 4: gather codebook rows -> quantized output (NCHW), loss partials.
__global__ __launch_bounds__(256) void gather_kernel(
    const float* __restrict__ latent, const float* __restrict__ codebook,
    const int* __restrict__ idx_ws, float* __restrict__ out,
    float* __restrict__ partials)
{
    int gid = blockIdx.x * 256 + threadIdx.x;
    int o = gid * 4;                       // flat NCHW index, 4 consecutive w
    int w0 = o & 31;
    int h  = (o >> 5) & 31;
    int c  = (o >> 10) & 255;
    int b  = o >> 18;
    int nb = (b << 10) + (h << 5) + w0;    // token index of first element

    float4 x = *(const float4*)&latent[o];
    float4 q;
    q.x = codebook[(size_t)idx_ws[nb + 0] * DIMS + c];
    q.y = codebook[(size_t)idx_ws[nb + 1] * DIMS + c];
    q.z = codebook[(size_t)idx_ws[nb + 2] * DIMS + c];
    q.w = codebook[(size_t)idx_ws[nb + 3] * DIMS + c];
    *(float4*)&out[o] = q;

    float dx = q.x - x.x, dy = q.y - x.y, dz = q.z - x.z, dw = q.w - x.w;
    float s = dx*dx + dy*dy + dz*dz + dw*dw;
    #pragma unroll
    for (int m = 32; m >= 1; m >>= 1) s += __shfl_xor(s, m, 64);

    __shared__ float wsum[4];
    int lane = threadIdx.x & 63, wv = threadIdx.x >> 6;
    if (lane == 0) wsum[wv] = s;
    __syncthreads();
    if (threadIdx.x == 0)
        partials[blockIdx.x] = wsum[0] + wsum[1] + wsum[2] + wsum[3];
}

// ---------------------------------------------------------------------------
// Kernel 5: final loss reduction (double accumulate), write both scalars.
__global__ void loss_kernel(const float* __restrict__ partials, float* __restrict__ out) {
    __shared__ double sd[256];
    double s = 0.0;
    #pragma unroll
    for (int r = 0; r < GATHER_BLOCKS / 256; ++r)
        s += (double)partials[threadIdx.x + r * 256];
    sd[threadIdx.x] = s;
    __syncthreads();
    for (int k = 128; k >= 1; k >>= 1) {
        if (threadIdx.x < k) sd[threadIdx.x] += sd[threadIdx.x + k];
        __syncthreads();
    }
    if (threadIdx.x == 0) {
        float loss = (float)(sd[0] / (double)((size_t)NTOK * DIMS));
        out[(size_t)NTOK * DIMS + 0] = loss;  // codebook_loss
        out[(size_t)NTOK * DIMS + 1] = loss;  // commitment_loss (same forward value)
    }
}

// ---------------------------------------------------------------------------
extern "C" void kernel_launch(void* const* d_in, const int* in_sizes, int n_in,
                              void* d_out, int out_size, void* d_ws, size_t ws_size,
                              hipStream_t stream) {
    (void)in_sizes; (void)n_in; (void)out_size; (void)ws_size;
    const float* latent   = (const float*)d_in[0];
    const float* codebook = (const float*)d_in[1];
    float* out = (float*)d_out;
    char*  ws  = (char*)d_ws;

    float* cb2   = (float*)(ws + WS_CB2);
    float* bestv = (float*)(ws + WS_BESTV);
    int*   besti = (int*)(ws + WS_BESTI);
    int*   idx   = (int*)(ws + WS_IDX);
    float* part  = (float*)(ws + WS_PART);

    cb2_kernel<<<KCODES / 4, 256, 0, stream>>>(codebook, cb2);
    argmin_kernel<<<(NTOK / MBLK) * NSPLIT, 256, 0, stream>>>(latent, codebook, cb2, bestv, besti);
    combine_kernel<<<NTOK / 256, 256, 0, stream>>>(bestv, besti, idx);
    gather_kernel<<<GATHER_BLOCKS, 256, 0, stream>>>(latent, codebook, idx, out, part);
    loss_kernel<<<1, 256, 0, stream>>>(part, out);
}

// Round 2
// 1084.743 us; speedup vs baseline: 4.4866x; 4.4866x over previous
//
#include <hip/hip_runtime.h>
#include <math.h>
#include <float.h>

// Problem constants
#define BATCH 16
#define CHN   256
#define HH    32
#define WW    32
#define NTOK  (BATCH*HH*WW)   // 16384 tokens
#define DIMS  256             // embedding dim
#define KCODES 8192           // codebook entries

// Argmin GEMM tiling
#define MBLK 128                          // tokens per block
#define NSPLIT 2                          // code-range splits (grid = 128*2 = 256 blocks)
#define CODES_PER_SPLIT (KCODES/NSPLIT)   // 4096
#define CCHUNK 256                        // codes per chunk (tile N)
#define NCHUNKS (CODES_PER_SPLIT/CCHUNK)  // 16
#define KSTEP 16                          // dims per B stage
#define NKK (DIMS/KSTEP)                  // 16
#define BSTR 260                          // B_t row stride in floats (bank spread, 16B-aligned)

#define GATHER_BLOCKS 4096

// Workspace layout (bytes)
#define WS_CB2   0
#define WS_BESTV (32768)
#define WS_BESTI (WS_BESTV + NSPLIT*NTOK*4)
#define WS_IDX   (WS_BESTI + NSPLIT*NTOK*4)
#define WS_PART  (WS_IDX + NTOK*4)
// total = 360448 + 16384 = 376832 bytes (< harness ws_size)

// ---------------------------------------------------------------------------
// Kernel 1: cb2[k] = sum_d codebook[k][d]^2. One wave per row.
__global__ void cb2_kernel(const float* __restrict__ codebook, float* __restrict__ cb2) {
    int wv   = threadIdx.x >> 6;          // 0..3
    int lane = threadIdx.x & 63;
    int row  = blockIdx.x * 4 + wv;       // grid = 2048 blocks -> 8192 rows
    const float4 v = *(const float4*)&codebook[(size_t)row * DIMS + lane * 4];
    float s = v.x*v.x + v.y*v.y + v.z*v.z + v.w*v.w;
    #pragma unroll
    for (int m = 32; m >= 1; m >>= 1) s += __shfl_xor(s, m, 64);
    if (lane == 0) cb2[row] = s;
}

// ---------------------------------------------------------------------------
// Kernel 2: fused distance-GEMM + running argmin.
// Block: 512 threads (8 waves), 128 tokens x 4096 codes.
// A (latent tile) transposed in LDS once: At[k][t], 128 KB.
// B (codebook chunk) staged per 16-dim step: Bt[k][c], reg-prefetched.
// score = cb2[k] - 2 * dot(x, c_k)  (x^2 omitted: constant per row)
__global__ __launch_bounds__(512, 2) void argmin_kernel(
    const float* __restrict__ latent, const float* __restrict__ codebook,
    const float* __restrict__ cb2,
    float* __restrict__ bestv_ws, int* __restrict__ besti_ws)
{
    __shared__ float smem[256*128 + KSTEP*BSTR];  // 131072 + 16640 B = 147712 B
    float* At = smem;                 // [k][t], stride 128
    float* Bt = smem + 256*128;       // [k_local][c], stride BSTR

    const int tid = threadIdx.x;
    const int bm = blockIdx.x >> 1;       // token block 0..127
    const int js = blockIdx.x & 1;        // code split 0..1
    const int n0 = bm * MBLK;
    const int bb  = n0 >> 10;             // batch index
    const int hw0 = n0 & 1023;            // h*W+w base (multiple of 128)
    const int cbase = js * CODES_PER_SPLIT;

    // wave/lane decomposition: wave tile 64 tok x 64 codes, lane tile 8x8
    const int w    = tid >> 6;            // 0..7
    const int wm   = w & 1;               // token half
    const int wn   = w >> 1;              // code quarter
    const int lane = tid & 63;
    const int lr   = lane & 7;
    const int lc   = lane >> 3;
    const int trow = wm*64 + lr*8;        // token base within tile (0..120)
    const int ccol = wn*64 + lc*8;        // chunk-local code base (0..248)

    // ---- stage At once: thread loads float4 at (k0+16r, t4)
    {
        const int t4 = (tid & 31) * 4;
        const int k0 = tid >> 5;          // 0..15
        const float* src = latent + (size_t)bb*(CHN*HH*WW) + hw0 + t4;
        #pragma unroll
        for (int r = 0; r < 16; ++r) {
            int k = k0 + 16*r;
            float4 v = *(const float4*)&src[(size_t)k * (HH*WW)];
            *(float4*)&At[k*128 + t4] = v;
        }
    }

    // ---- B staging map: thread owns (dim-quad bdq, code bc) and (bc+128)
    const int bdq = tid & 3;              // 0..3 -> dims 4*bdq..4*bdq+3 within KSTEP
    const int bc  = tid >> 2;             // 0..127
    float4 pb0, pb1;                      // prefetch regs
    {
        const float* cbp = codebook + (size_t)(cbase + bc)*DIMS + 4*bdq;
        pb0 = *(const float4*)&cbp[0];
        pb1 = *(const float4*)&cbp[(size_t)128*DIMS];
    }

    float bestv[8];
    int   besti[8];
    #pragma unroll
    for (int i = 0; i < 8; ++i) { bestv[i] = FLT_MAX; besti[i] = 0x7fffffff; }

    float acc[8][8];

    for (int ii = 0; ii < NCHUNKS*NKK; ++ii) {
        const int chunk = ii >> 4;
        const int kk = (ii & 15) * KSTEP;

        if ((ii & 15) == 0) {
            #pragma unroll
            for (int i = 0; i < 8; ++i)
                #pragma unroll
                for (int j = 0; j < 8; ++j) acc[i][j] = 0.0f;
        }

        __syncthreads();   // previous compute done -> Bt free (also covers At staging on ii=0)
        {
            const float* p0 = (const float*)&pb0;
            const float* p1 = (const float*)&pb1;
            #pragma unroll
            for (int e = 0; e < 4; ++e) {
                Bt[(4*bdq+e)*BSTR + bc]       = p0[e];
                Bt[(4*bdq+e)*BSTR + 128 + bc] = p1[e];
            }
        }
        __syncthreads();

        // prefetch next stage (hidden under the 1024-FMA compute below)
        if (ii + 1 < NCHUNKS*NKK) {
            const int nc = (ii+1) >> 4;
            const int nk = ((ii+1) & 15) * KSTEP;
            const float* cbp = codebook + (size_t)(cbase + nc*CCHUNK + bc)*DIMS + nk + 4*bdq;
            pb0 = *(const float4*)&cbp[0];
            pb1 = *(const float4*)&cbp[(size_t)128*DIMS];
        }

        #pragma unroll
        for (int k = 0; k < KSTEP; ++k) {
            const float4 a0 = *(const float4*)&At[(kk + k)*128 + trow];
            const float4 a1 = *(const float4*)&At[(kk + k)*128 + trow + 4];
            const float4 b0 = *(const float4*)&Bt[k*BSTR + ccol];
            const float4 b1 = *(const float4*)&Bt[k*BSTR + ccol + 4];
            const float av[8] = {a0.x,a0.y,a0.z,a0.w,a1.x,a1.y,a1.z,a1.w};
            const float bv[8] = {b0.x,b0.y,b0.z,b0.w,b1.x,b1.y,b1.z,b1.w};
            #pragma unroll
            for (int i = 0; i < 8; ++i)
                #pragma unroll
                for (int j = 0; j < 8; ++j)
                    acc[i][j] = fmaf(av[i], bv[j], acc[i][j]);
        }

        if ((ii & 15) == 15) {
            // fold cb2, update running argmin. Codes visited in strictly
            // ascending order per thread -> strict '<' == np.argmin tie rule.
            const int code0 = cbase + chunk*CCHUNK + ccol;
            #pragma unroll
            for (int j = 0; j < 8; ++j) {
                const float c2 = cb2[code0 + j];
                #pragma unroll
                for (int i = 0; i < 8; ++i) {
                    const float v = c2 - 2.0f * acc[i][j];
                    if (v < bestv[i]) { bestv[i] = v; besti[i] = code0 + j; }
                }
            }
        }
    }

    // ---- reduce: across the 8 lc lanes (xor 8/16/32), then across wn via LDS
    __syncthreads();                       // Bt reusable as reduction scratch
    float* red_v = Bt;                     // [4][128]
    int*   red_i = (int*)(Bt + 512);       // [4][128]
    #pragma unroll
    for (int i = 0; i < 8; ++i) {
        float v = bestv[i]; int ix = besti[i];
        #pragma unroll
        for (int m = 8; m <= 32; m <<= 1) {
            float ov = __shfl_xor(v, m, 64);
            int   oi = __shfl_xor(ix, m, 64);
            if (ov < v || (ov == v && oi < ix)) { v = ov; ix = oi; }
        }
        if (lc == 0) {
            red_v[wn*128 + trow + i] = v;
            red_i[wn*128 + trow + i] = ix;
        }
    }
    __syncthreads();
    if (tid < 128) {
        float v = red_v[tid]; int ix = red_i[tid];
        #pragma unroll
        for (int q = 1; q < 4; ++q) {
            float ov = red_v[q*128 + tid];
            int   oi = red_i[q*128 + tid];
            if (ov < v || (ov == v && oi < ix)) { v = ov; ix = oi; }
        }
        bestv_ws[js*NTOK + n0 + tid] = v;
        besti_ws[js*NTOK + n0 + tid] = ix;
    }
}

// ---------------------------------------------------------------------------
// Kernel 3: combine the NSPLIT partial argmins per token.
__global__ void combine_kernel(const float* __restrict__ bestv_ws,
                               const int* __restrict__ besti_ws,
                               int* __restrict__ idx_ws)
{
    int n = blockIdx.x * 256 + threadIdx.x;
    float v = bestv_ws[n];
    int  ix = besti_ws[n];
    #pragma unroll
    for (int js = 1; js < NSPLIT; ++js) {
        float ov = bestv_ws[js * NTOK + n];
        int   oi = besti_ws[js * NTOK + n];
        if (ov < v || (ov == v && oi < ix)) { v = ov; ix = oi; }
    }
    idx_ws[n] = ix;
}

// ---------------------------------------------------------------------------
// Kernel 4: gather codebook rows -> quantized output (NCHW), loss partials.
__global__ __launch_bounds__(256) void gather_kernel(
    const float* __restrict__ latent, const float* __restrict__ codebook,
    const int* __restrict__ idx_ws, float* __restrict__ out,
    float* __restrict__ partials)
{
    int gid = blockIdx.x * 256 + threadIdx.x;
    int o = gid * 4;                       // flat NCHW index, 4 consecutive w
    int w0 = o & 31;
    int h  = (o >> 5) & 31;
    int c  = (o >> 10) & 255;
    int b  = o >> 18;
    int nb = (b << 10) + (h << 5) + w0;    // token index of first element

    float4 x = *(const float4*)&latent[o];
    float4 q;
    q.x = codebook[(size_t)idx_ws[nb + 0] * DIMS + c];
    q.y = codebook[(size_t)idx_ws[nb + 1] * DIMS + c];
    q.z = codebook[(size_t)idx_ws[nb + 2] * DIMS + c];
    q.w = codebook[(size_t)idx_ws[nb + 3] * DIMS + c];
    *(float4*)&out[o] = q;

    float dx = q.x - x.x, dy = q.y - x.y, dz = q.z - x.z, dw = q.w - x.w;
    float s = dx*dx + dy*dy + dz*dz + dw*dw;
    #pragma unroll
    for (int m = 32; m >= 1; m >>= 1) s += __shfl_xor(s, m, 64);

    __shared__ float wsum[4];
    int lane = threadIdx.x & 63, wv = threadIdx.x >> 6;
    if (lane == 0) wsum[wv] = s;
    __syncthreads();
    if (threadIdx.x == 0)
        partials[blockIdx.x] = wsum[0] + wsum[1] + wsum[2] + wsum[3];
}

// ---------------------------------------------------------------------------
// Kernel 5: final loss reduction (double accumulate), write both scalars.
__global__ void loss_kernel(const float* __restrict__ partials, float* __restrict__ out) {
    __shared__ double sd[256];
    double s = 0.0;
    #pragma unroll
    for (int r = 0; r < GATHER_BLOCKS / 256; ++r)
        s += (double)partials[threadIdx.x + r * 256];
    sd[threadIdx.x] = s;
    __syncthreads();
    for (int k = 128; k >= 1; k >>= 1) {
        if (threadIdx.x < k) sd[threadIdx.x] += sd[threadIdx.x + k];
        __syncthreads();
    }
    if (threadIdx.x == 0) {
        float loss = (float)(sd[0] / (double)((size_t)NTOK * DIMS));
        out[(size_t)NTOK * DIMS + 0] = loss;  // codebook_loss
        out[(size_t)NTOK * DIMS + 1] = loss;  // commitment_loss (same forward value)
    }
}

// ---------------------------------------------------------------------------
extern "C" void kernel_launch(void* const* d_in, const int* in_sizes, int n_in,
                              void* d_out, int out_size, void* d_ws, size_t ws_size,
                              hipStream_t stream) {
    (void)in_sizes; (void)n_in; (void)out_size; (void)ws_size;
    const float* latent   = (const float*)d_in[0];
    const float* codebook = (const float*)d_in[1];
    float* out = (float*)d_out;
    char*  ws  = (char*)d_ws;

    float* cb2   = (float*)(ws + WS_CB2);
    float* bestv = (float*)(ws + WS_BESTV);
    int*   besti = (int*)(ws + WS_BESTI);
    int*   idx   = (int*)(ws + WS_IDX);
    float* part  = (float*)(ws + WS_PART);

    cb2_kernel<<<KCODES / 4, 256, 0, stream>>>(codebook, cb2);
    argmin_kernel<<<(NTOK / MBLK) * NSPLIT, 512, 0, stream>>>(latent, codebook, cb2, bestv, besti);
    combine_kernel<<<NTOK / 256, 256, 0, stream>>>(bestv, besti, idx);
    gather_kernel<<<GATHER_BLOCKS, 256, 0, stream>>>(latent, codebook, idx, out, part);
    loss_kernel<<<1, 256, 0, stream>>>(part, out);
}

// Round 4
// 236.503 us; speedup vs baseline: 20.5784x; 4.5866x over previous
//
#include <hip/hip_runtime.h>
#include <math.h>
#include <float.h>

// Problem constants
#define BATCH 16
#define CHN   256
#define HH    32
#define WW    32
#define NTOK  (BATCH*HH*WW)   // 16384 tokens
#define DIMS  256             // embedding dim
#define KCODES 8192           // codebook entries

// Argmin tiling
#define MBLK 128                          // tokens per block (8 waves x 16)
#define NSPLIT 4                          // grid = 128*4 = 512 blocks (2/CU)
#define CODES_PER_SPLIT (KCODES/NSPLIT)   // 2048
#define CCHUNK 64                         // codes per chunk
#define NCHUNKS (CODES_PER_SPLIT/CCHUNK)  // 32
#define BROW 512                          // packed B row length in f16 (Bh|Bl)
#define BTSTR 136                         // LDS B row stride in f16 (128+8 pad)

#define GATHER_BLOCKS 4096

// Workspace layout (bytes) — same as round 1 (proven OK)
#define WS_CB2   0
#define WS_BESTV (32768)
#define WS_BESTI (WS_BESTV + NSPLIT*NTOK*4)
#define WS_IDX   (WS_BESTI + NSPLIT*NTOK*4)
#define WS_PART  (WS_IDX + NTOK*4)

typedef _Float16 f16;
typedef f16 f16x8 __attribute__((ext_vector_type(8)));
typedef float f32x4 __attribute__((ext_vector_type(4)));

// ---------------------------------------------------------------------------
// Kernel 1: cb2[k] = sum_d codebook[k][d]^2 (fp32, unscaled). One wave per row.
__global__ void cb2_kernel(const float* __restrict__ codebook, float* __restrict__ cb2) {
    int wv   = threadIdx.x >> 6;
    int lane = threadIdx.x & 63;
    int row  = blockIdx.x * 4 + wv;
    const float4 v = *(const float4*)&codebook[(size_t)row * DIMS + lane * 4];
    float s = v.x*v.x + v.y*v.y + v.z*v.z + v.w*v.w;
    #pragma unroll
    for (int m = 32; m >= 1; m >>= 1) s += __shfl_xor(s, m, 64);
    if (lane == 0) cb2[row] = s;
}

// ---------------------------------------------------------------------------
// Kernel 2: pack codebook into f16 limb planes: row[0:256]=Bh, [256:512]=Bl.
// Scaled x256 (argmin-invariant; keeps Bl out of f16-subnormal range).
__global__ void bpack_kernel(const float* __restrict__ codebook, f16* __restrict__ bpp) {
    int code = blockIdx.x;
    int k = threadIdx.x;
    float x = codebook[(size_t)code * DIMS + k] * 256.0f;
    f16 h = (f16)x;
    f16 l = (f16)(x - (float)h);
    f16* row = bpp + (size_t)code * BROW;
    row[k] = h;
    row[256 + k] = l;
}

// ---------------------------------------------------------------------------
// Kernel 3: MFMA distance-GEMM + running argmin (3-pass f16 limb split:
// dot approx = Ah*Bh + Al*Bh + Ah*Bl, fp32 accumulate).
// 8 waves x 16 tokens; per chunk (64 codes): 4 stage-steps of 128 virtual-k,
// single LDS buffer, two barriers per step (textbook). Bh windows are used
// by BOTH Ah and Al passes while resident.
__global__ __launch_bounds__(512, 2) void argmin_kernel(
    const float* __restrict__ latent, const f16* __restrict__ bpp,
    const float* __restrict__ cb2,
    float* __restrict__ bestv_ws, int* __restrict__ besti_ws)
{
    __shared__ f16 Bt[CCHUNK * BTSTR];    // 64 x 136 f16 = 17408 B

    const int tid = threadIdx.x;
    const int wv = tid >> 6, l = tid & 63;
    const int bm = blockIdx.x >> 2;        // token block 0..127
    const int js = blockIdx.x & 3;         // code split 0..3
    const int n0 = bm * MBLK;
    const int bb = n0 >> 10, hw0 = n0 & 1023;
    const int code_base = js * CODES_PER_SPLIT;

    // ---- A prologue: direct global->register limb fragments.
    // Wave wv owns tokens n0 + wv*16 + (0..15); lane l&15 = token row,
    // l>>4 = k-block; fragment reg j -> k = kst*32 + (l>>4)*8 + j.
    f16x8 Ah[8], Al[8];
    {
        const float* latb = latent + (size_t)bb * (CHN*HH*WW) + hw0 + wv*16 + (l & 15);
        #pragma unroll
        for (int kst = 0; kst < 8; ++kst) {
            f16x8 h, lo;
            #pragma unroll
            for (int j = 0; j < 8; ++j) {
                float v = latb[(size_t)(kst*32 + ((l >> 4) << 3) + j) * (HH*WW)];
                f16 hh = (f16)v;
                h[j] = hh;
                lo[j] = (f16)(v - (float)hh);
            }
            Ah[kst] = h;
            Al[kst] = lo;
        }
    }

    f32x4 acc[4];
    float bv[4];
    int   bi[4];
    #pragma unroll
    for (int nf = 0; nf < 4; ++nf) acc[nf] = (f32x4)0.0f;
    #pragma unroll
    for (int r = 0; r < 4; ++r) { bv[r] = FLT_MAX; bi[r] = 0x7fffffff; }

    // staging map: thread -> (row = tid>>3, 16B slots tid&7 and (tid&7)+8)
    const int srow = tid >> 3;
    const int s8   = tid & 7;

    for (int chunk = 0; chunk < NCHUNKS; ++chunk) {
        #pragma unroll
        for (int sidx = 0; sidx < 4; ++sidx) {
            // sidx 0,1: Bh k-windows [0:128),[128:256) -> Ah AND Al passes
            // sidx 2,3: Bl k-windows                   -> Ah pass only
            __syncthreads();   // prior step's compute done -> Bt free
            {
                const float4* src = (const float4*)(bpp
                    + (size_t)(code_base + chunk*CCHUNK + srow) * BROW + sidx*128);
                float4 v0 = src[s8];
                float4 v1 = src[s8 + 8];
                *(float4*)&Bt[srow*BTSTR + s8*8]     = v0;
                *(float4*)&Bt[srow*BTSTR + (s8+8)*8] = v1;
            }
            __syncthreads();

            const int kb4 = (sidx & 1) * 4;
            #pragma unroll
            for (int ksub = 0; ksub < 4; ++ksub) {
                f16x8 bf[4];
                #pragma unroll
                for (int nf = 0; nf < 4; ++nf)
                    bf[nf] = *(const f16x8*)&Bt[(nf*16 + (l & 15))*BTSTR
                                                + (ksub*4 + (l >> 4))*8];
                const int kst = kb4 + ksub;
                #pragma unroll
                for (int nf = 0; nf < 4; ++nf)
                    acc[nf] = __builtin_amdgcn_mfma_f32_16x16x32_f16(Ah[kst], bf[nf], acc[nf], 0, 0, 0);
                if (sidx < 2) {
                    #pragma unroll
                    for (int nf = 0; nf < 4; ++nf)
                        acc[nf] = __builtin_amdgcn_mfma_f32_16x16x32_f16(Al[kst], bf[nf], acc[nf], 0, 0, 0);
                }
            }
        }

        // fold chunk scores (codes ascend per lane -> strict '<' == np.argmin)
        const int code0 = code_base + chunk*CCHUNK;
        #pragma unroll
        for (int nf = 0; nf < 4; ++nf) {
            const int code = code0 + nf*16 + (l & 15);
            const float c2 = cb2[code];
            #pragma unroll
            for (int r = 0; r < 4; ++r) {
                float v = fmaf(acc[nf][r], -0.0078125f, c2);  // c2 - 2*dot
                if (v < bv[r]) { bv[r] = v; bi[r] = code; }
                acc[nf][r] = 0.0f;
            }
        }
    }

    // ---- reduce across the 16 code-lanes; write per-token best ----
    #pragma unroll
    for (int r = 0; r < 4; ++r) {
        float v = bv[r];
        int ix = bi[r];
        #pragma unroll
        for (int m = 1; m <= 8; m <<= 1) {
            float ov = __shfl_xor(v, m, 64);
            int   oi = __shfl_xor(ix, m, 64);
            if (ov < v || (ov == v && oi < ix)) { v = ov; ix = oi; }
        }
        if ((l & 15) == 0) {
            int t = n0 + wv*16 + ((l >> 4) << 2) + r;   // D row = (l>>4)*4 + r
            bestv_ws[js*NTOK + t] = v;
            besti_ws[js*NTOK + t] = ix;
        }
    }
}

// ---------------------------------------------------------------------------
// Kernel 4: combine the NSPLIT partial argmins per token.
__global__ void combine_kernel(const float* __restrict__ bestv_ws,
                               const int* __restrict__ besti_ws,
                               int* __restrict__ idx_ws)
{
    int n = blockIdx.x * 256 + threadIdx.x;
    float v = bestv_ws[n];
    int  ix = besti_ws[n];
    #pragma unroll
    for (int js = 1; js < NSPLIT; ++js) {
        float ov = bestv_ws[js * NTOK + n];
        int   oi = besti_ws[js * NTOK + n];
        if (ov < v || (ov == v && oi < ix)) { v = ov; ix = oi; }
    }
    idx_ws[n] = ix;
}

// ---------------------------------------------------------------------------
// Kernel 5: gather codebook rows -> quantized output (NCHW), loss partials.
__global__ __launch_bounds__(256) void gather_kernel(
    const float* __restrict__ latent, const float* __restrict__ codebook,
    const int* __restrict__ idx_ws, float* __restrict__ out,
    float* __restrict__ partials)
{
    int gid = blockIdx.x * 256 + threadIdx.x;
    int o = gid * 4;                       // flat NCHW index, 4 consecutive w
    int w0 = o & 31;
    int h  = (o >> 5) & 31;
    int c  = (o >> 10) & 255;
    int b  = o >> 18;
    int nb = (b << 10) + (h << 5) + w0;    // token index of first element

    float4 x = *(const float4*)&latent[o];
    float4 q;
    q.x = codebook[(size_t)idx_ws[nb + 0] * DIMS + c];
    q.y = codebook[(size_t)idx_ws[nb + 1] * DIMS + c];
    q.z = codebook[(size_t)idx_ws[nb + 2] * DIMS + c];
    q.w = codebook[(size_t)idx_ws[nb + 3] * DIMS + c];
    *(float4*)&out[o] = q;

    float dx = q.x - x.x, dy = q.y - x.y, dz = q.z - x.z, dw = q.w - x.w;
    float s = dx*dx + dy*dy + dz*dz + dw*dw;
    #pragma unroll
    for (int m = 32; m >= 1; m >>= 1) s += __shfl_xor(s, m, 64);

    __shared__ float wsum[4];
    int lane = threadIdx.x & 63, wv = threadIdx.x >> 6;
    if (lane == 0) wsum[wv] = s;
    __syncthreads();
    if (threadIdx.x == 0)
        partials[blockIdx.x] = wsum[0] + wsum[1] + wsum[2] + wsum[3];
}

// ---------------------------------------------------------------------------
// Kernel 6: final loss reduction (double accumulate), write both scalars.
__global__ void loss_kernel(const float* __restrict__ partials, float* __restrict__ out) {
    __shared__ double sd[256];
    double s = 0.0;
    #pragma unroll
    for (int r = 0; r < GATHER_BLOCKS / 256; ++r)
        s += (double)partials[threadIdx.x + r * 256];
    sd[threadIdx.x] = s;
    __syncthreads();
    for (int k = 128; k >= 1; k >>= 1) {
        if (threadIdx.x < k) sd[threadIdx.x] += sd[threadIdx.x + k];
        __syncthreads();
    }
    if (threadIdx.x == 0) {
        float loss = (float)(sd[0] / (double)((size_t)NTOK * DIMS));
        out[(size_t)NTOK * DIMS + 0] = loss;  // codebook_loss
        out[(size_t)NTOK * DIMS + 1] = loss;  // commitment_loss (same fwd value)
    }
}

// ---------------------------------------------------------------------------
extern "C" void kernel_launch(void* const* d_in, const int* in_sizes, int n_in,
                              void* d_out, int out_size, void* d_ws, size_t ws_size,
                              hipStream_t stream) {
    (void)in_sizes; (void)n_in; (void)out_size; (void)ws_size;
    const float* latent   = (const float*)d_in[0];
    const float* codebook = (const float*)d_in[1];
    float* out = (float*)d_out;
    char*  ws  = (char*)d_ws;

    float* cb2   = (float*)(ws + WS_CB2);
    float* bestv = (float*)(ws + WS_BESTV);
    int*   besti = (int*)(ws + WS_BESTI);
    int*   idx   = (int*)(ws + WS_IDX);
    float* part  = (float*)(ws + WS_PART);

    // B limb planes live in d_out scratch (8.39 MB < 16.78 MB); the gather
    // kernel fully overwrites d_out afterwards.
    f16* bpp = (f16*)d_out;

    cb2_kernel<<<KCODES / 4, 256, 0, stream>>>(codebook, cb2);
    bpack_kernel<<<KCODES, 256, 0, stream>>>(codebook, bpp);
    argmin_kernel<<<(NTOK / MBLK) * NSPLIT, 512, 0, stream>>>(latent, bpp, cb2, bestv, besti);
    combine_kernel<<<NTOK / 256, 256, 0, stream>>>(bestv, besti, idx);
    gather_kernel<<<GATHER_BLOCKS, 256, 0, stream>>>(latent, codebook, idx, out, part);
    loss_kernel<<<1, 256, 0, stream>>>(part, out);
}